// Round 12
// baseline (354.140 us; speedup 1.0000x reference)
//
#include <hip/hip_runtime.h>
#include <hip/hip_bf16.h>

// ---------------- problem constants ----------------
#define HW    4096      // H*W
#define TT    8         // time steps

typedef _Float16 halfx8 __attribute__((ext_vector_type(8)));
typedef float    floatx4 __attribute__((ext_vector_type(4)));
typedef float    floatx2 __attribute__((ext_vector_type(2)));

__device__ inline float fast_exp2(float x) {
#if __has_builtin(__builtin_amdgcn_exp2f)
    return __builtin_amdgcn_exp2f(x);
#else
    return __builtin_exp2f(x);
#endif
}
__device__ inline float fast_rcp(float x) {
#if __has_builtin(__builtin_amdgcn_rcpf)
    return __builtin_amdgcn_rcpf(x);
#else
    return 1.0f / x;
#endif
}
__device__ inline floatx2 exp2x2(floatx2 x) {
    floatx2 r; r.x = fast_exp2(x.x); r.y = fast_exp2(x.y); return r;
}
__device__ inline floatx2 rcpx2(floatx2 x) {
    floatx2 r; r.x = fast_rcp(x.x); r.y = fast_rcp(x.y); return r;
}
__device__ inline floatx2 fsig2(floatx2 x) {          // sigmoid
    return rcpx2(exp2x2(x * -1.44269504088896f) + 1.0f);
}
__device__ inline floatx2 ftanh2(floatx2 x) {         // tanh
    floatx2 r = rcpx2(exp2x2(x * 2.88539008177793f) + 1.0f);
    return r * -2.0f + 1.0f;
}

union pack8 { _Float16 h[8]; uint4 u; };

// ---------------- single fused kernel: conv_in + LSTM + conv_out ----------------
// Resource model (r7-r11): wave-slot capacity is register-driven: total unified
// VGPR+AGPR in (102,128] -> 4 waves/SIMD = 16 waves/CU. 8-wave blocks tile that
// exactly (r9/r10: 2 blocks); r11's 10-wave block couldn't pack twice -> 1 block.
// This round sheds the AGPR margin: the s-projection MFMA pair (extra acc tuple
// + 2 frag loads live at loop head) is replaced by a 16-lane shfl_xor reduction
// over the fp32 h values each lane already holds (VALU mix is free here --
// r5/r8/r10 all neutral). If total drops <=102 -> 5 waves/SIMD -> the 640-thread
// config packs 2 x 10 = 20 waves/CU.
// t-loop otherwise r7-verbatim (asm clobber pins B-frags in LDS -> low VGPR).
// LDS = 68096 B -> 2 blocks/CU. NO forced min-waves bound (r2/r3 spills).
__global__ __launch_bounds__(640) void lstm_kernel(
    const float* __restrict__ hin,    // (B, 64, HW)
    const float* __restrict__ w_in,   // (64, 64)
    const float* __restrict__ b_in,   // (64,)
    const float* __restrict__ w_ih,   // (256, 1)
    const float* __restrict__ w_hh,   // (256, 64)
    const float* __restrict__ b_ih,   // (256,)
    const float* __restrict__ b_hh,   // (256,)
    const float* __restrict__ w_s,    // (1, 64)
    const float* __restrict__ b_s_p,  // (1,)
    const float* __restrict__ w_out,  // (64, 64)
    const float* __restrict__ b_out,  // (64,)
    float* __restrict__ out) {        // (B, 64, HW)
    __shared__ uint4 wfrag_lds[2048];                  // 32768 B: 32 w_hh frags
    __shared__ floatx2 wxb_lds[256];                   // 2048 B: per-gate {w_x, bias}
    __shared__ __align__(16) float x_lds[1280];        // 5120 B: [t][seq160]
    __shared__ __align__(16) _Float16 h_lds[11520];    // 23040 B: 10 waves x 16 x 72;
                                                       //   aliased for w_in/w_out staging
    __shared__ __align__(16) float stile[1280];        // 5120 B: [c64][px20]; hin then s
    float* hreg = (float*)h_lds;                       // w staging alias (stride 65)

    int tid = threadIdx.x;
    int ptile = blockIdx.x;               // 0..204 (tail tile 204 has 16 px)
    int b     = blockIdx.y;
    int p0  = ptile * 20;
    int npx = (ptile == 204) ? 16 : 20;

    int lane = tid & 63;
    int wv   = tid >> 6;                  // 0..9
    int s    = lane & 15;
    int q    = lane >> 4;

    // ---- repack w_hh -> B-fragment-ordered f16 (frag fi=nb*2+kc, entry e=fi*64+l;
    //      lane l holds B[k=kc*32+(l>>4)*8+j][n=(l&15)] = w_hh[gate=(l&15)+16nb][hid=k])
    #pragma unroll
    for (int i = 0; i < 4; ++i) {
        int e = tid + 640 * i;
        if (e < 2048) {
            int l  = e & 63;
            int fi = e >> 6;
            int nb = fi >> 1, kc = fi & 1;
            int gate = (l & 15) + 16 * nb;
            int hid  = kc * 32 + (l >> 4) * 8;
            const floatx4* src = (const floatx4*)&w_hh[gate * 64 + hid];
            floatx4 v0 = src[0], v1 = src[1];
            pack8 p;
            p.h[0] = (_Float16)v0[0]; p.h[1] = (_Float16)v0[1];
            p.h[2] = (_Float16)v0[2]; p.h[3] = (_Float16)v0[3];
            p.h[4] = (_Float16)v1[0]; p.h[5] = (_Float16)v1[1];
            p.h[6] = (_Float16)v1[2]; p.h[7] = (_Float16)v1[3];
            wfrag_lds[e] = p.u;
        }
    }
    // per-gate {w_x, bias}
    if (tid < 256) {
        floatx2 v; v.x = w_ih[tid]; v.y = b_ih[tid] + b_hh[tid];
        wxb_lds[tid] = v;
    }
    // stage w_in into h-region, rows stride 65 (bank-spread)
    #pragma unroll
    for (int i = 0; i < 7; ++i) {
        int idx = tid + 640 * i;
        if (idx < 4096) hreg[(idx >> 6) * 65 + (idx & 63)] = w_in[idx];
    }
    // stage hin tile (64 ch x 20 px); tail px padded with 0
    #pragma unroll
    for (int i = 0; i < 2; ++i) {
        int idx = tid + 640 * i;
        if (idx < 1280) {
            int cc = idx / 20, px = idx % 20;
            stile[idx] = (px < npx) ? hin[(b * 64 + cc) * HW + p0 + px] : 0.0f;
        }
    }
    __syncthreads();

    // ---- conv_in: thread -> (px, tq, g); computes x[t=tq] and x[t=tq+4] for seq g*20+px
    {
        int px   = tid % 20;
        int rest = tid / 20;              // 0..31
        int tq = rest & 3, g = rest >> 2;
        floatx2 xacc; xacc.x = b_in[g * 8 + tq]; xacc.y = b_in[g * 8 + tq + 4];
        #pragma unroll 8
        for (int cc = 0; cc < 64; ++cc) {
            float hv = stile[cc * 20 + px];
            floatx2 w;
            w.x = hreg[(g * 8 + tq) * 65 + cc];
            w.y = hreg[(g * 8 + tq + 4) * 65 + cc];
            xacc.x += w.x * hv;
            xacc.y += w.y * hv;
        }
        x_lds[tq * 160 + g * 20 + px]       = xacc.x;   // x[t][seq]
        x_lds[(tq + 4) * 160 + g * 20 + px] = xacc.y;
    }
    __syncthreads();   // conv_in reads of hreg (w_in) done before zeroing h
    // zero h state (5760 u32)
    #pragma unroll
    for (int i = 0; i < 9; ++i) {
        int idx = tid + 640 * i;
        if (idx < 5760) ((unsigned*)h_lds)[idx] = 0u;
    }
    __syncthreads();

    // per-lane s-write bases: seq wv*16+q*4+r -> stile index gr*160 + t*20 + pxr
    int sbx[4];
    #pragma unroll
    for (int r = 0; r < 4; ++r) {
        int sg = wv * 16 + q * 4 + r;
        sbx[r] = (sg / 20) * 160 + (sg % 20);
    }
    // per-lane s-projection weights: w_s[s + 16*hb]
    float wsv_r[4];
    #pragma unroll
    for (int hb = 0; hb < 4; ++hb) wsv_r[hb] = w_s[s + 16 * hb];

    _Float16* hrow = h_lds + wv * 16 * 72;
    float bs = b_s_p[0];

    float c_st[4][4];
    #pragma unroll
    for (int hb = 0; hb < 4; ++hb)
        #pragma unroll
        for (int r = 0; r < 4; ++r) c_st[hb][r] = 0.0f;

    for (int t = 0; t < TT; ++t) {
        // Hard memory barrier: forbids caching LDS B-frags in registers
        // across iterations (r7: this is what keeps VGPR low -> high occupancy).
        asm volatile("" ::: "memory");

        halfx8 a0 = *(const halfx8*)(hrow + s * 72 + q * 8);        // k = 0..31
        halfx8 a1 = *(const halfx8*)(hrow + s * 72 + q * 8 + 32);   // k = 32..63

        floatx4 xv = *(const floatx4*)&x_lds[t * 160 + wv * 16 + q * 4];
        floatx2 xlo; xlo.x = xv[0]; xlo.y = xv[1];
        floatx2 xhi; xhi.x = xv[2]; xhi.y = xv[3];

        float sp[4] = {0.f, 0.f, 0.f, 0.f};   // s-projection partials (this lane's 4 hids)

        #pragma unroll
        for (int hb = 0; hb < 4; ++hb) {
            floatx4 acc[4];
            #pragma unroll
            for (int gi = 0; gi < 4; ++gi) {
                int nb = hb + 4 * gi;
                floatx2 wb = wxb_lds[s + 16 * nb];
                floatx2 lo = xlo * wb.x + wb.y;     // x*w_x + bias as C init (pk_fma)
                floatx2 hi = xhi * wb.x + wb.y;
                floatx4 a = {lo.x, lo.y, hi.x, hi.y};
                halfx8 b0 = *(const halfx8*)&wfrag_lds[(nb * 2 + 0) * 64 + lane];
                halfx8 b1 = *(const halfx8*)&wfrag_lds[(nb * 2 + 1) * 64 + lane];
                a = __builtin_amdgcn_mfma_f32_16x16x32_f16(a0, b0, a, 0, 0, 0);
                a = __builtin_amdgcn_mfma_f32_16x16x32_f16(a1, b1, a, 0, 0, 0);
                acc[gi] = a;
            }
            int s16 = s + 16 * hb;
            _Float16* wp = hrow + (q * 4) * 72 + s16;
            float wsv = wsv_r[hb];
            #pragma unroll
            for (int p = 0; p < 2; ++p) {
                int r0 = 2 * p;
                floatx2 iv; iv.x = acc[0][r0]; iv.y = acc[0][r0 + 1]; iv = fsig2(iv);
                floatx2 fv; fv.x = acc[1][r0]; fv.y = acc[1][r0 + 1]; fv = fsig2(fv);
                floatx2 gv; gv.x = acc[2][r0]; gv.y = acc[2][r0 + 1]; gv = ftanh2(gv);
                floatx2 ov; ov.x = acc[3][r0]; ov.y = acc[3][r0 + 1]; ov = fsig2(ov);
                floatx2 cp; cp.x = c_st[hb][r0]; cp.y = c_st[hb][r0 + 1];
                floatx2 c = fv * cp + iv * gv;
                c_st[hb][r0] = c.x; c_st[hb][r0 + 1] = c.y;
                floatx2 hn = ov * ftanh2(c);
                sp[r0]     += hn.x * wsv;             // s-proj partial (fp32 h)
                sp[r0 + 1] += hn.y * wsv;
                wp[(r0 + 0) * 72] = (_Float16)hn.x;   // state for t+1
                wp[(r0 + 1) * 72] = (_Float16)hn.y;
            }
        }
        // reduce sp over the 16 lanes of this q-group (hid index s) and store s_t
        #pragma unroll
        for (int m = 1; m < 16; m <<= 1) {
            sp[0] += __shfl_xor(sp[0], m, 64);
            sp[1] += __shfl_xor(sp[1], m, 64);
            sp[2] += __shfl_xor(sp[2], m, 64);
            sp[3] += __shfl_xor(sp[3], m, 64);
        }
        if (s == 0) {
            int toff = t * 20;
            stile[sbx[0] + toff] = sp[0] + bs;
            stile[sbx[1] + toff] = sp[1] + bs;
            stile[sbx[2] + toff] = sp[2] + bs;
            stile[sbx[3] + toff] = sp[3] + bs;
        }
    }
    __syncthreads();   // all h_lds reads + stile writes done

    // stage w_out into h-region (h state dead now), rows stride 65
    #pragma unroll
    for (int i = 0; i < 7; ++i) {
        int idx = tid + 640 * i;
        if (idx < 4096) hreg[(idx >> 6) * 65 + (idx & 63)] = w_out[idx];
    }
    __syncthreads();

    // ---- conv_out epilogue: out[b][o][p0+px] = sum_c w_out[o][c]*stile[c][px] + b_out[o]
    {
        int px = tid % 20;
        int o  = tid / 20;                 // 0..31 -> outputs o and o+32
        floatx2 acc; acc.x = b_out[o]; acc.y = b_out[o + 32];
        #pragma unroll 8
        for (int c = 0; c < 64; ++c) {
            float sv = stile[c * 20 + px];
            acc.x += hreg[o * 65 + c] * sv;
            acc.y += hreg[(o + 32) * 65 + c] * sv;
        }
        if (px < npx) {
            out[(b * 64 + o) * HW + p0 + px]      = acc.x;
            out[(b * 64 + o + 32) * HW + p0 + px] = acc.y;
        }
    }
}

extern "C" void kernel_launch(void* const* d_in, const int* in_sizes, int n_in,
                              void* d_out, int out_size, void* d_ws, size_t ws_size,
                              hipStream_t stream) {
    const float* h     = (const float*)d_in[0];
    const float* w_in  = (const float*)d_in[1];
    const float* b_in  = (const float*)d_in[2];
    const float* w_ih  = (const float*)d_in[3];
    const float* w_hh  = (const float*)d_in[4];
    const float* b_ih  = (const float*)d_in[5];
    const float* b_hh  = (const float*)d_in[6];
    const float* w_s   = (const float*)d_in[7];
    const float* b_s   = (const float*)d_in[8];
    const float* w_out = (const float*)d_in[9];
    const float* b_out = (const float*)d_in[10];
    float* out = (float*)d_out;
    (void)d_ws; (void)ws_size;

    // single fused kernel. 205 pixel-tiles (204x20px + 1x16px) x 8 batches,
    // 640 threads (10 waves) per block.
    lstm_kernel<<<dim3(205, 8), 640, 0, stream>>>(h, w_in, b_in, w_ih, w_hh,
                                                  b_ih, b_hh, w_s, b_s,
                                                  w_out, b_out, out);
}

// Round 14
// 245.859 us; speedup vs baseline: 1.4404x; 1.4404x over previous
//
#include <hip/hip_runtime.h>
#include <hip/hip_bf16.h>

// ---------------- problem constants ----------------
#define HW    4096      // H*W
#define TT    8         // time steps

// ws layout (floats)
constexpr int OFF_WFRAG = 0;        // 34 frags * 64 lanes * 16B = 8704 floats
constexpr int OFF_WXB   = 8704;     // 256 float2 = 512 floats {w_x, bias}

typedef _Float16 halfx8 __attribute__((ext_vector_type(8)));
typedef float    floatx4 __attribute__((ext_vector_type(4)));
typedef float    floatx2 __attribute__((ext_vector_type(2)));

__device__ inline float fast_exp2(float x) {
#if __has_builtin(__builtin_amdgcn_exp2f)
    return __builtin_amdgcn_exp2f(x);
#else
    return __builtin_exp2f(x);
#endif
}
__device__ inline float fast_rcp(float x) {
#if __has_builtin(__builtin_amdgcn_rcpf)
    return __builtin_amdgcn_rcpf(x);
#else
    return 1.0f / x;
#endif
}
__device__ inline floatx2 exp2x2(floatx2 x) {
    floatx2 r; r.x = fast_exp2(x.x); r.y = fast_exp2(x.y); return r;
}
__device__ inline floatx2 rcpx2(floatx2 x) {
    floatx2 r; r.x = fast_rcp(x.x); r.y = fast_rcp(x.y); return r;
}
__device__ inline floatx2 fsig2(floatx2 x) {          // sigmoid
    return rcpx2(exp2x2(x * -1.44269504088896f) + 1.0f);
}
__device__ inline floatx2 ftanh2(floatx2 x) {         // tanh
    floatx2 r = rcpx2(exp2x2(x * 2.88539008177793f) + 1.0f);
    return r * -2.0f + 1.0f;
}

union pack8 { _Float16 h[8]; uint4 u; };

// ---------------- prep: repack weights into d_ws (2 blocks) ----------------
__global__ __launch_bounds__(256) void prep_kernel(
    const float* __restrict__ w_ih,  const float* __restrict__ w_hh,
    const float* __restrict__ b_ih,  const float* __restrict__ b_hh,
    const float* __restrict__ w_s,   float* __restrict__ ws_f) {
    int tid = threadIdx.x;
    if (blockIdx.x == 0) {
        // w_hh -> B-fragment-ordered f16. frag fi = nb*2+kc; entry e = fi*64 + lane.
        // lane l holds B[k=kc*32+(l>>4)*8+j][n=(l&15)] = w_hh[gate=(l&15)+16nb][hid=k]
        uint4* wf = (uint4*)(ws_f + OFF_WFRAG);
        #pragma unroll
        for (int i = 0; i < 8; ++i) {
            int e  = tid + 256 * i;
            int l  = e & 63;
            int fi = e >> 6;
            int nb = fi >> 1, kc = fi & 1;
            int gate = (l & 15) + 16 * nb;
            int hid  = kc * 32 + (l >> 4) * 8;
            const float* src = w_hh + gate * 64 + hid;
            pack8 p;
            #pragma unroll
            for (int j = 0; j < 8; ++j) p.h[j] = (_Float16)src[j];
            wf[e] = p.u;
        }
        // s-projection fragments (entries 2048..2175): B[k][0] = w_s[k], other cols 0
        if (tid < 128) {
            int l = tid & 63, kc = tid >> 6;
            pack8 p;
            #pragma unroll
            for (int j = 0; j < 8; ++j) p.h[j] = (_Float16)0.0f;
            if ((l & 15) == 0) {
                #pragma unroll
                for (int j = 0; j < 8; ++j)
                    p.h[j] = (_Float16)w_s[kc * 32 + (l >> 4) * 8 + j];
            }
            wf[2048 + kc * 64 + l] = p.u;
        }
    } else {
        // {w_x, bias} pairs
        floatx2* wxb = (floatx2*)(ws_f + OFF_WXB);
        floatx2 v; v.x = w_ih[tid]; v.y = b_ih[tid] + b_hh[tid];
        wxb[tid] = v;
    }
}

// ---------------- fully fused conv_in + LSTM + conv_out ----------------
// 512 threads = 8 waves = ONE 16-pixel tile x ALL 8 groups (wave wv == group).
// Consolidation of every verified win:
//  - r7/r9 t-loop recipe: asm memory clobber pins B-frags in LDS -> 52 arch
//    VGPR; plain fsig2/ftanh2 (batched-rcp never cut VALU-pipe cycles: r5/r8/
//    r10 neutral); s-projection via MFMA (r12 shuffle version was SLOWER).
//  - stride-65 w staging (r10: bank conflicts 3.28M -> 1.1M).
//  - w_in/w_out staged in the h-state LDS region (r11 alias trick): w_in dies
//    before h is zeroed; w_out staged after the last h read. LDS = 63488 B.
//  - r13 BUG FIX: x_lds needs 128 floats/group ([g][t8][px16]); the 512-float
//    g*64 version overflowed into group g+1 (absmax 4.2e-3).
// Occupancy model (r7-r12): total unified VGPR+AGPR in (102,128] -> 4 waves/
// SIMD; 8-wave blocks tile the 16-wave/CU ceiling exactly. 640-thr blocks
// cannot pack twice (r11/r12) -> 512 is the packing optimum.
// NO forced min-waves bound (r2/r3: arch/AGPR split + massive spills).
__global__ __launch_bounds__(512) void lstm_kernel(
    const float* __restrict__ hin,    // (B, 64, HW)
    const float* __restrict__ ws_f,   // prep tables
    const float* __restrict__ w_in,   // (64, 64)
    const float* __restrict__ b_in,   // (64,)
    const float* __restrict__ b_s_p,  // (1,)
    const float* __restrict__ w_out,  // (64, 64)
    const float* __restrict__ b_out,  // (64,)
    float* __restrict__ out) {        // (B, 64, HW)
    __shared__ uint4 wfrag_lds[2176];                  // 34816 B: 32 w_hh + 2 w_s frags
    __shared__ floatx2 wxb_lds[256];                   // 2048 B: per-gate {w_x, bias}
    __shared__ __align__(16) float x_lds[1024];        // 4096 B: [g][t8][px16]
    __shared__ __align__(16) _Float16 h_lds[9216];     // 18432 B: 8 waves x 16 x 72;
                                                       //   aliased for w_in/w_out staging
    __shared__ __align__(16) float stile[1024];        // 4096 B: [c64][px16]; hin then s
    float* hreg = (float*)h_lds;                       // w staging alias (stride 65)

    int tid = threadIdx.x;
    int ptile = blockIdx.x;               // 0..255
    int b     = blockIdx.y;
    int p0 = ptile * 16;

    int lane = tid & 63;
    int wv   = tid >> 6;                  // 0..7 == group g
    int g    = wv;
    int s    = lane & 15;                 // pixel-local == MFMA seq row
    int q    = lane >> 4;

    // stage weight fragments (shared by all 8 waves)
    const uint4* wfg = (const uint4*)(ws_f + OFF_WFRAG);
    #pragma unroll
    for (int i = 0; i < 5; ++i) {
        int e = tid + 512 * i;
        if (e < 2176) wfrag_lds[e] = wfg[e];
    }
    if (tid < 256) wxb_lds[tid] = ((const floatx2*)(ws_f + OFF_WXB))[tid];
    // stage w_in into h-region, rows stride 65 (65 == 1 mod 32 -> bank-spread)
    #pragma unroll
    for (int i = 0; i < 8; ++i) {
        int idx = tid + 512 * i;          // 0..4095
        hreg[(idx >> 6) * 65 + (idx & 63)] = w_in[idx];
    }
    // stage hin tile (64 ch x 16 px)
    if (tid < 256) {
        int cc = tid >> 2, f4 = tid & 3;
        ((floatx4*)stile)[tid] = *(const floatx4*)&hin[(b * 64 + cc) * HW + p0 + f4 * 4];
    }
    __syncthreads();

    // ---- conv_in (per wave, own group): x[g][t][px] = sum_c w_in[g8+t][c]*hin[c][px] + b_in
    {
        floatx2 xacc; xacc.x = b_in[g * 8 + q]; xacc.y = b_in[g * 8 + q + 4];
        #pragma unroll 8
        for (int cc = 0; cc < 64; ++cc) {
            float hv = stile[cc * 16 + s];
            floatx2 w;
            w.x = hreg[(g * 8 + q) * 65 + cc];
            w.y = hreg[(g * 8 + q + 4) * 65 + cc];
            xacc.x += w.x * hv;
            xacc.y += w.y * hv;
        }
        x_lds[g * 128 + q * 16 + s]       = xacc.x;    // [g][t][px], 128 floats/group
        x_lds[g * 128 + (q + 4) * 16 + s] = xacc.y;
    }
    __syncthreads();   // conv_in reads of hreg (w_in) + stile done
    // zero h state (4608 u32) -- overwrites the w_in staging
    #pragma unroll
    for (int i = 0; i < 9; ++i)
        ((unsigned*)h_lds)[tid + 512 * i] = 0u;
    __syncthreads();

    _Float16* hrow = h_lds + wv * 16 * 72;
    float bs = b_s_p[0];

    float c_st[4][4];
    #pragma unroll
    for (int hb = 0; hb < 4; ++hb)
        #pragma unroll
        for (int r = 0; r < 4; ++r) c_st[hb][r] = 0.0f;

    for (int t = 0; t < TT; ++t) {
        // Hard memory barrier: forbids caching LDS B-frags in registers
        // across iterations (r7: this is what keeps VGPR at 52 -> 16 waves/CU).
        asm volatile("" ::: "memory");

        halfx8 a0 = *(const halfx8*)(hrow + s * 72 + q * 8);        // k = 0..31
        halfx8 a1 = *(const halfx8*)(hrow + s * 72 + q * 8 + 32);   // k = 32..63

        // s_{t-1} = h_t @ w_s via MFMA (col 0 only); lanes s==0 hold seqs q*4+r
        if (t > 0) {
            halfx8 sb0 = *(const halfx8*)&wfrag_lds[2048 + lane];
            halfx8 sb1 = *(const halfx8*)&wfrag_lds[2112 + lane];
            floatx4 sa = {0.f, 0.f, 0.f, 0.f};
            sa = __builtin_amdgcn_mfma_f32_16x16x32_f16(a0, sb0, sa, 0, 0, 0);
            sa = __builtin_amdgcn_mfma_f32_16x16x32_f16(a1, sb1, sa, 0, 0, 0);
            if (s == 0) {
                floatx4 o4 = {sa[0] + bs, sa[1] + bs, sa[2] + bs, sa[3] + bs};
                *(floatx4*)&stile[(g * 8 + (t - 1)) * 16 + q * 4] = o4;
            }
        }

        floatx4 xv = *(const floatx4*)&x_lds[g * 128 + t * 16 + q * 4];
        floatx2 xlo; xlo.x = xv[0]; xlo.y = xv[1];
        floatx2 xhi; xhi.x = xv[2]; xhi.y = xv[3];

        #pragma unroll
        for (int hb = 0; hb < 4; ++hb) {
            floatx4 acc[4];
            #pragma unroll
            for (int gi = 0; gi < 4; ++gi) {
                int nb = hb + 4 * gi;
                floatx2 wb = wxb_lds[s + 16 * nb];
                floatx2 lo = xlo * wb.x + wb.y;     // x*w_x + bias as C init (pk_fma)
                floatx2 hi = xhi * wb.x + wb.y;
                floatx4 a = {lo.x, lo.y, hi.x, hi.y};
                halfx8 b0 = *(const halfx8*)&wfrag_lds[(nb * 2 + 0) * 64 + lane];
                halfx8 b1 = *(const halfx8*)&wfrag_lds[(nb * 2 + 1) * 64 + lane];
                a = __builtin_amdgcn_mfma_f32_16x16x32_f16(a0, b0, a, 0, 0, 0);
                a = __builtin_amdgcn_mfma_f32_16x16x32_f16(a1, b1, a, 0, 0, 0);
                acc[gi] = a;
            }
            int s16 = s + 16 * hb;
            _Float16* wp = hrow + (q * 4) * 72 + s16;
            #pragma unroll
            for (int p = 0; p < 2; ++p) {
                int r0 = 2 * p;
                floatx2 iv; iv.x = acc[0][r0]; iv.y = acc[0][r0 + 1]; iv = fsig2(iv);
                floatx2 fv; fv.x = acc[1][r0]; fv.y = acc[1][r0 + 1]; fv = fsig2(fv);
                floatx2 gv; gv.x = acc[2][r0]; gv.y = acc[2][r0 + 1]; gv = ftanh2(gv);
                floatx2 ov; ov.x = acc[3][r0]; ov.y = acc[3][r0 + 1]; ov = fsig2(ov);
                floatx2 cp; cp.x = c_st[hb][r0]; cp.y = c_st[hb][r0 + 1];
                floatx2 c = fv * cp + iv * gv;
                c_st[hb][r0] = c.x; c_st[hb][r0 + 1] = c.y;
                floatx2 hn = ov * ftanh2(c);
                wp[(r0 + 0) * 72] = (_Float16)hn.x;   // state for t+1
                wp[(r0 + 1) * 72] = (_Float16)hn.y;
            }
        }
    }
    // final s_7 from h_8
    {
        asm volatile("" ::: "memory");
        halfx8 a0 = *(const halfx8*)(hrow + s * 72 + q * 8);
        halfx8 a1 = *(const halfx8*)(hrow + s * 72 + q * 8 + 32);
        halfx8 sb0 = *(const halfx8*)&wfrag_lds[2048 + lane];
        halfx8 sb1 = *(const halfx8*)&wfrag_lds[2112 + lane];
        floatx4 sa = {0.f, 0.f, 0.f, 0.f};
        sa = __builtin_amdgcn_mfma_f32_16x16x32_f16(a0, sb0, sa, 0, 0, 0);
        sa = __builtin_amdgcn_mfma_f32_16x16x32_f16(a1, sb1, sa, 0, 0, 0);
        if (s == 0) {
            floatx4 o4 = {sa[0] + bs, sa[1] + bs, sa[2] + bs, sa[3] + bs};
            *(floatx4*)&stile[(g * 8 + 7) * 16 + q * 4] = o4;
        }
    }
    __syncthreads();   // all h_lds reads + stile s-writes done

    // stage w_out into h-region (h state dead now), rows stride 65
    #pragma unroll
    for (int i = 0; i < 8; ++i) {
        int idx = tid + 512 * i;
        hreg[(idx >> 6) * 65 + (idx & 63)] = w_out[idx];
    }
    __syncthreads();

    // ---- conv_out epilogue: out[b][o][p0+px] = sum_c w_out[o][c]*stile[c][px] + b_out[o]
    {
        int px = tid & 15;
        int oo = tid >> 4;                 // 0..31 -> outputs oo and oo+32
        floatx2 acc; acc.x = b_out[oo]; acc.y = b_out[oo + 32];
        #pragma unroll 8
        for (int c = 0; c < 64; ++c) {
            float sv = stile[c * 16 + px];
            acc.x += hreg[oo * 65 + c] * sv;
            acc.y += hreg[(oo + 32) * 65 + c] * sv;
        }
        out[(b * 64 + oo) * HW + p0 + px]      = acc.x;
        out[(b * 64 + oo + 32) * HW + p0 + px] = acc.y;
    }
}

extern "C" void kernel_launch(void* const* d_in, const int* in_sizes, int n_in,
                              void* d_out, int out_size, void* d_ws, size_t ws_size,
                              hipStream_t stream) {
    const float* h     = (const float*)d_in[0];
    const float* w_in  = (const float*)d_in[1];
    const float* b_in  = (const float*)d_in[2];
    const float* w_ih  = (const float*)d_in[3];
    const float* w_hh  = (const float*)d_in[4];
    const float* b_ih  = (const float*)d_in[5];
    const float* b_hh  = (const float*)d_in[6];
    const float* w_s   = (const float*)d_in[7];
    const float* b_s   = (const float*)d_in[8];
    const float* w_out = (const float*)d_in[9];
    const float* b_out = (const float*)d_in[10];
    float* out = (float*)d_out;
    float* ws  = (float*)d_ws;

    prep_kernel<<<2, 256, 0, stream>>>(w_ih, w_hh, b_ih, b_hh, w_s, ws);
    // fused conv_in + LSTM + conv_out. 256 pixel-tiles x 8 batches, 512 threads.
    lstm_kernel<<<dim3(256, 8), 512, 0, stream>>>(h, ws, w_in, b_in, b_s,
                                                  w_out, b_out, out);
}